// Round 1
// baseline (15313.799 us; speedup 1.0000x reference)
//
#include <hip/hip_runtime.h>
#include <hip/hip_fp16.h>

// Gated LSTM: B=64, T=2048, I=128, H=256, O=1.
// Persistent kernel: 64 WGs = 8 batch-groups (g = bid&7 -> same XCD if round-robin)
//                         x 8 N-slices (p = bid>>3).
// Each WG: 256 threads, batches g*8..g*8+7, h-outputs j = p*32..p*32+31.
// W slice ([W_ih;W_hh] rows for its 4x32 gate-rows, K=384) lives in VGPRs as
// f16 MFMA B-fragments (96 VGPRs/thread) -- zero per-step weight traffic.
// Per step: stage gated x + exchanged h into LDS A-tile -> 96 MFMAs ->
// epilogue (c,h update, c in registers) -> h exchange via agent-scope atomics
// (double-buffered, monotonic step-count flags).

#define NB 64
#define NT 2048
#define NI 128
#define NH 256

typedef _Float16 h8_t __attribute__((ext_vector_type(8)));
typedef _Float16 h4_t __attribute__((ext_vector_type(4)));
typedef float f4_t __attribute__((ext_vector_type(4)));

__device__ __forceinline__ float sigm(float x) {
  return __builtin_amdgcn_rcpf(1.f + __expf(-x));
}
__device__ __forceinline__ float tanh_f(float x) {
  // tanh(x) = 1 - 2/(1+e^{2x}); saturates correctly at +/-inf
  return 1.f - 2.f * __builtin_amdgcn_rcpf(1.f + __expf(2.f * x));
}

// ex layout (floats): [buf2][g8][p8][b8][j32]  strides: j1,b32,p256,g2048,buf16384
// flags (u32): [g8][p8] at stride 32 (128B lines), after ex (byte offset 131072)

__launch_bounds__(256, 1)
__global__ void lstm_persist(
    const float* __restrict__ xd, const float* __restrict__ w,
    const float* __restrict__ W_ih, const float* __restrict__ b_ih,
    const float* __restrict__ W_hh, const float* __restrict__ b_hh,
    const float* __restrict__ W_out, const float* __restrict__ b_out,
    float* __restrict__ out, float* ex, unsigned* flags)
{
  const int bid = blockIdx.x;
  const int g = bid & 7;        // batch group
  const int p = bid >> 3;       // N-slice
  const int tid = threadIdx.x;
  const int lane = tid & 63;
  const int wv = tid >> 6;      // wave 0..3

  // A-tile: [m=batch (8 used, 8..15 stay zero)][k: 0..127 gated x, 128..383 h]
  // row pad to 392 f16 (784B = 49*16B, 16B-aligned rows, balanced banks)
  __shared__ _Float16 Alds[16][392];
  // Z: [local z-row r = j_local*4 + gate][m]  (+1 pad col)
  __shared__ float Zlds[128][17];

  for (int i = tid; i < 16 * 392; i += 256) (&Alds[0][0])[i] = (_Float16)0.f;

  const int q  = lane >> 4;     // 0..3
  const int cc = lane & 15;

  // ---- W B-fragments, resident in registers ----
  // local z-row r: j_local = r>>2, gate = r&3 -> global row R = gate*256 + p*32 + j_local
  // B-frag lane mapping: n = lane&15 -> r = 16*tile + cc ; k = kt*32 + q*8 + j
  h8_t wf[2][12];
  for (int nt = 0; nt < 2; ++nt) {
    int r = 16 * (2 * wv + nt) + cc;
    int R = (r & 3) * NH + p * 32 + (r >> 2);
    for (int kt = 0; kt < 12; ++kt) {
      int k = kt * 32 + q * 8;   // k<128 iff kt<4 (whole 8-run on one side)
      const float* s = (k < NI) ? (W_ih + (size_t)R * NI + k)
                                : (W_hh + (size_t)R * NH + (k - NI));
      f4_t lo = *(const f4_t*)s;
      f4_t hi = *(const f4_t*)(s + 4);
      h8_t hh;
      hh[0] = (_Float16)lo[0]; hh[1] = (_Float16)lo[1];
      hh[2] = (_Float16)lo[2]; hh[3] = (_Float16)lo[3];
      hh[4] = (_Float16)hi[0]; hh[5] = (_Float16)hi[1];
      hh[6] = (_Float16)hi[2]; hh[7] = (_Float16)hi[3];
      wf[nt][kt] = hh;
    }
  }

  // epilogue identity: thread = (b_local, j_local)
  const int bl = tid >> 5;      // 0..7
  const int jj = tid & 31;      // 0..31
  float bias[4];
  #pragma unroll
  for (int gate = 0; gate < 4; ++gate)
    bias[gate] = b_ih[gate * NH + p * 32 + jj] + b_hh[gate * NH + p * 32 + jj];

  float creg = 0.f;
  const size_t xbase = ((size_t)(g * 8 + bl) * NT) * NI + jj * 4;

  __syncthreads();   // Alds zeros + everything staged before first step

  for (int t = 0; t < NT; ++t) {
    // ---- stage gated x_t (loads overlap the flag spin below) ----
    f4_t xv = *(const f4_t*)(xd + xbase + (size_t)t * NI);
    f4_t wg = *(const f4_t*)(w  + xbase + (size_t)t * NI);
    h4_t gx;
    gx[0] = (_Float16)(xv[0] * sigm(wg[0]));
    gx[1] = (_Float16)(xv[1] * sigm(wg[1]));
    gx[2] = (_Float16)(xv[2] * sigm(wg[2]));
    gx[3] = (_Float16)(xv[3] * sigm(wg[3]));

    // ---- wait for partners' h^{(t)} ----
    if (t > 0 && tid < 7) {
      int ps = tid < p ? tid : tid + 1;
      unsigned* f = flags + (g * 8 + ps) * 32;
      while (__hip_atomic_load(f, __ATOMIC_ACQUIRE, __HIP_MEMORY_SCOPE_AGENT)
             < (unsigned)t)
        __builtin_amdgcn_s_sleep(1);
    }
    *(h4_t*)(&Alds[bl][jj * 4]) = gx;
    __syncthreads();
    if (t > 0) {
      // read 7 remote h slices from buf[t&1] -> Alds h-region
      #pragma unroll
      for (int s7 = 0; s7 < 7; ++s7) {
        int ps = s7 < p ? s7 : s7 + 1;
        float hv = __hip_atomic_load(
            ex + (t & 1) * 16384 + g * 2048 + ps * 256 + bl * 32 + jj,
            __ATOMIC_RELAXED, __HIP_MEMORY_SCOPE_AGENT);
        Alds[bl][NI + ps * 32 + jj] = (_Float16)hv;
      }
      __syncthreads();
    }

    // ---- MFMA: Z[m=batch][n=local z-row], K=384 ----
    f4_t acc0 = {0.f, 0.f, 0.f, 0.f}, acc1 = {0.f, 0.f, 0.f, 0.f};
    #pragma unroll
    for (int kt = 0; kt < 12; ++kt) {
      h8_t af = *(const h8_t*)(&Alds[cc][kt * 32 + q * 8]);
      acc0 = __builtin_amdgcn_mfma_f32_16x16x32_f16(af, wf[0][kt], acc0, 0, 0, 0);
      acc1 = __builtin_amdgcn_mfma_f32_16x16x32_f16(af, wf[1][kt], acc1, 0, 0, 0);
    }
    // C layout: col = lane&15 (n), row = q*4+reg (m). Only m<8 are real batches.
    if (q < 2) {
      #pragma unroll
      for (int r = 0; r < 4; ++r) {
        Zlds[16 * (2 * wv)     + cc][q * 4 + r] = acc0[r];
        Zlds[16 * (2 * wv + 1) + cc][q * 4 + r] = acc1[r];
      }
    }
    __syncthreads();

    // ---- epilogue: gate nonlinearities, state update ----
    float zi = Zlds[jj * 4 + 0][bl] + bias[0];
    float zf = Zlds[jj * 4 + 1][bl] + bias[1];
    float zg = Zlds[jj * 4 + 2][bl] + bias[2];
    float zo = Zlds[jj * 4 + 3][bl] + bias[3];
    creg = sigm(zf) * creg + sigm(zi) * tanh_f(zg);
    float hreg = sigm(zo) * tanh_f(creg);
    Alds[bl][NI + p * 32 + jj] = (_Float16)hreg;          // own slice for t+1
    __hip_atomic_store(
        ex + ((t + 1) & 1) * 16384 + g * 2048 + p * 256 + bl * 32 + jj, hreg,
        __ATOMIC_RELAXED, __HIP_MEMORY_SCOPE_AGENT);
    __threadfence();       // drain h stores to device scope
    __syncthreads();       // all waves' stores drained (vmcnt0 before barrier)
    if (tid == 0)
      __hip_atomic_store(flags + (g * 8 + p) * 32, (unsigned)(t + 1),
                         __ATOMIC_RELEASE, __HIP_MEMORY_SCOPE_AGENT);
  }

  // ---- output: out[b] = h_T . W_out + b_out, by p==0 WGs ----
  if (p == 0) {
    if (tid < 7) {
      unsigned* f = flags + (g * 8 + (tid + 1)) * 32;
      while (__hip_atomic_load(f, __ATOMIC_ACQUIRE, __HIP_MEMORY_SCOPE_AGENT)
             < (unsigned)NT)
        __builtin_amdgcn_s_sleep(1);
    }
    __syncthreads();
    float sum = 0.f;
    #pragma unroll
    for (int s = 0; s < 8; ++s) {   // h^(T) lives in buf[NT&1 == 0]
      float hv = __hip_atomic_load(
          ex + g * 2048 + s * 256 + bl * 32 + jj,
          __ATOMIC_RELAXED, __HIP_MEMORY_SCOPE_AGENT);
      sum += hv * W_out[s * 32 + jj];
    }
    #pragma unroll
    for (int m = 16; m >= 1; m >>= 1) sum += __shfl_xor(sum, m, 64);
    if (jj == 0) out[g * 8 + bl] = sum + b_out[0];
  }
}

extern "C" void kernel_launch(void* const* d_in, const int* in_sizes, int n_in,
                              void* d_out, int out_size, void* d_ws, size_t ws_size,
                              hipStream_t stream) {
  (void)in_sizes; (void)n_in; (void)out_size; (void)ws_size;
  const float* xd    = (const float*)d_in[0];
  const float* w     = (const float*)d_in[1];
  const float* W_ih  = (const float*)d_in[2];
  const float* b_ih  = (const float*)d_in[3];
  const float* W_hh  = (const float*)d_in[4];
  const float* b_hh  = (const float*)d_in[5];
  const float* W_out = (const float*)d_in[6];
  const float* b_out = (const float*)d_in[7];
  float* ex = (float*)d_ws;
  unsigned* flags = (unsigned*)((char*)d_ws + 32768 * sizeof(float));
  // ws usage: 128 KB exchange + 8 KB flags. Flags MUST be zeroed (ws is
  // poisoned 0xAA before every launch); async memset is graph-capture safe.
  hipMemsetAsync(d_ws, 0, 32768 * sizeof(float) + 64 * 32 * sizeof(unsigned),
                 stream);
  lstm_persist<<<dim3(64), dim3(256), 0, stream>>>(
      xd, w, W_ih, b_ih, W_hh, b_hh, W_out, b_out, (float*)d_out, ex, flags);
}

// Round 2
// 4353.466 us; speedup vs baseline: 3.5176x; 3.5176x over previous
//
#include <hip/hip_runtime.h>
#include <hip/hip_fp16.h>
#include <stdint.h>

// Gated LSTM: B=64, T=2048, I=128, H=256, O=1.
// Persistent kernel: 64 WGs = 8 batch-groups x 8 N-slices (p = bid>>3).
// Each WG: 256 threads, batches g*8..g*8+7, h-outputs j = p*32..p*32+31.
// W slice ([W_ih;W_hh] rows for its 4x32 gate-rows, K=384) lives in VGPRs as
// f16 MFMA B-fragments -- zero per-step weight traffic.
//
// R2 change (sync protocol): h exchange is TAG-EMBEDDED 64-bit relaxed
// agent-scope atomics {tag=t+1 : f32 h}. Single-copy atomicity makes
// value+tag self-consistent, so there are NO fences, NO flags, NO
// acquire/release (R1's threadfence + acquire-polls caused per-step L2
// wb/inv storms -> 7.5us/step). Double-buffer by t&1; monotone tags make
// ABA impossible; 0xAA ws poison (tag 0xAAAAAAAA > 2048) never aliases a
// valid tag, so no memset dispatch is needed.

#define NB 64
#define NT 2048
#define NI 128
#define NH 256

typedef _Float16 h8_t __attribute__((ext_vector_type(8)));
typedef _Float16 h4_t __attribute__((ext_vector_type(4)));
typedef float f4_t __attribute__((ext_vector_type(4)));

__device__ __forceinline__ float sigm(float x) {
  return __builtin_amdgcn_rcpf(1.f + __expf(-x));
}
__device__ __forceinline__ float tanh_f(float x) {
  return 1.f - 2.f * __builtin_amdgcn_rcpf(1.f + __expf(2.f * x));
}

// ex layout (uint64): [buf2][g8][p8][b8][j32]  strides: j1,b32,p256,g2048,buf16384

__launch_bounds__(256, 1)
__global__ void lstm_persist(
    const float* __restrict__ xd, const float* __restrict__ w,
    const float* __restrict__ W_ih, const float* __restrict__ b_ih,
    const float* __restrict__ W_hh, const float* __restrict__ b_hh,
    const float* __restrict__ W_out, const float* __restrict__ b_out,
    float* __restrict__ out, uint64_t* ex)
{
  const int bid = blockIdx.x;
  const int g = bid & 7;        // batch group
  const int p = bid >> 3;       // N-slice
  const int tid = threadIdx.x;
  const int lane = tid & 63;
  const int wv = tid >> 6;      // wave 0..3

  // A-tile: [m=batch (8 used, 8..15 stay zero)][k: 0..127 gated x, 128..383 h]
  __shared__ _Float16 Alds[16][392];
  // Z: [local z-row r = j_local*4 + gate][m]  (+1 pad col)
  __shared__ float Zlds[128][17];

  for (int i = tid; i < 16 * 392; i += 256) (&Alds[0][0])[i] = (_Float16)0.f;

  const int q  = lane >> 4;     // 0..3
  const int cc = lane & 15;

  // ---- W B-fragments, resident in registers ----
  h8_t wf[2][12];
  for (int nt = 0; nt < 2; ++nt) {
    int r = 16 * (2 * wv + nt) + cc;
    int R = (r & 3) * NH + p * 32 + (r >> 2);
    for (int kt = 0; kt < 12; ++kt) {
      int k = kt * 32 + q * 8;   // k<128 iff kt<4 (whole 8-run on one side)
      const float* s = (k < NI) ? (W_ih + (size_t)R * NI + k)
                                : (W_hh + (size_t)R * NH + (k - NI));
      f4_t lo = *(const f4_t*)s;
      f4_t hi = *(const f4_t*)(s + 4);
      h8_t hh;
      hh[0] = (_Float16)lo[0]; hh[1] = (_Float16)lo[1];
      hh[2] = (_Float16)lo[2]; hh[3] = (_Float16)lo[3];
      hh[4] = (_Float16)hi[0]; hh[5] = (_Float16)hi[1];
      hh[6] = (_Float16)hi[2]; hh[7] = (_Float16)hi[3];
      wf[nt][kt] = hh;
    }
  }

  // epilogue identity: thread = (b_local, j_local)
  const int bl = tid >> 5;      // 0..7
  const int jj = tid & 31;      // 0..31
  float bias[4];
  #pragma unroll
  for (int gate = 0; gate < 4; ++gate)
    bias[gate] = b_ih[gate * NH + p * 32 + jj] + b_hh[gate * NH + p * 32 + jj];

  // partner slot addresses (7 remote p-slices, same (bl,jj))
  int pidx[7];
  #pragma unroll
  for (int s7 = 0; s7 < 7; ++s7) {
    int ps = (s7 < p) ? s7 : s7 + 1;
    pidx[s7] = g * 2048 + ps * 256 + bl * 32 + jj;
  }
  uint64_t* const myslot0 = ex + g * 2048 + p * 256 + bl * 32 + jj;

  float creg = 0.f;
  float hreg = 0.f;
  const size_t xbase = ((size_t)(g * 8 + bl) * NT) * NI + jj * 4;

  __syncthreads();   // Alds zeros staged before first step

  for (int t = 0; t < NT; ++t) {
    // ---- issue gated-x loads (overlap the poll below) ----
    f4_t xv = *(const f4_t*)(xd + xbase + (size_t)t * NI);
    f4_t wg = *(const f4_t*)(w  + xbase + (size_t)t * NI);

    // ---- poll partners' tagged h^{(t)} (relaxed, payload-carried tag) ----
    if (t > 0) {
      const uint64_t* base = ex + (t & 1) * 16384;
      unsigned need = 0x7f;
      uint64_t v[7];
      while (need) {
        #pragma unroll
        for (int s7 = 0; s7 < 7; ++s7)
          if (need & (1u << s7))
            v[s7] = __hip_atomic_load(base + pidx[s7], __ATOMIC_RELAXED,
                                      __HIP_MEMORY_SCOPE_AGENT);
        #pragma unroll
        for (int s7 = 0; s7 < 7; ++s7)
          if ((need & (1u << s7)) && (unsigned)(v[s7] >> 32) == (unsigned)t) {
            int ps = (s7 < p) ? s7 : s7 + 1;
            Alds[bl][NI + ps * 32 + jj] =
                (_Float16)__uint_as_float((unsigned)v[s7]);
            need &= ~(1u << s7);
          }
      }
    }

    // ---- stage gated x_t ----
    h4_t gx;
    gx[0] = (_Float16)(xv[0] * sigm(wg[0]));
    gx[1] = (_Float16)(xv[1] * sigm(wg[1]));
    gx[2] = (_Float16)(xv[2] * sigm(wg[2]));
    gx[3] = (_Float16)(xv[3] * sigm(wg[3]));
    *(h4_t*)(&Alds[bl][jj * 4]) = gx;
    __syncthreads();                       // barrier 1: A-tile complete

    // ---- MFMA: Z[m=batch][n=local z-row], K=384 ----
    f4_t acc0 = {0.f, 0.f, 0.f, 0.f}, acc1 = {0.f, 0.f, 0.f, 0.f};
    #pragma unroll
    for (int kt = 0; kt < 12; ++kt) {
      h8_t af = *(const h8_t*)(&Alds[cc][kt * 32 + q * 8]);
      acc0 = __builtin_amdgcn_mfma_f32_16x16x32_f16(af, wf[0][kt], acc0, 0, 0, 0);
      acc1 = __builtin_amdgcn_mfma_f32_16x16x32_f16(af, wf[1][kt], acc1, 0, 0, 0);
    }
    // C layout: col = lane&15 (n), row = q*4+reg (m). Only m<8 are real.
    if (q < 2) {
      #pragma unroll
      for (int r = 0; r < 4; ++r) {
        Zlds[16 * (2 * wv)     + cc][q * 4 + r] = acc0[r];
        Zlds[16 * (2 * wv + 1) + cc][q * 4 + r] = acc1[r];
      }
    }
    __syncthreads();                       // barrier 2: Z complete

    // ---- epilogue: gates, state update, tagged publish ----
    float zi = Zlds[jj * 4 + 0][bl] + bias[0];
    float zf = Zlds[jj * 4 + 1][bl] + bias[1];
    float zg = Zlds[jj * 4 + 2][bl] + bias[2];
    float zo = Zlds[jj * 4 + 3][bl] + bias[3];
    creg = sigm(zf) * creg + sigm(zi) * tanh_f(zg);
    hreg = sigm(zo) * tanh_f(creg);
    Alds[bl][NI + p * 32 + jj] = (_Float16)hreg;   // own slice for t+1
    uint64_t pay = ((uint64_t)(unsigned)(t + 1) << 32) | __float_as_uint(hreg);
    __hip_atomic_store(myslot0 + ((t + 1) & 1) * 16384, pay,
                       __ATOMIC_RELAXED, __HIP_MEMORY_SCOPE_AGENT);
    // next iteration's barrier 1 orders this epilogue's Zlds reads and
    // Alds writes against the next MFMA phase -- no extra barrier here.
  }

  // ---- output: out[b] = h_T . W_out + b_out, by p==0 WGs ----
  // h^(NT) carries tag NT in buf[NT&1 == 0]; own slice is hreg.
  if (p == 0) {
    float sum = hreg * W_out[jj];          // s = 0 (own slice, p==0)
    unsigned need = 0x7f;
    uint64_t v[7];
    float hv[7];
    while (need) {
      #pragma unroll
      for (int s7 = 0; s7 < 7; ++s7)
        if (need & (1u << s7))
          v[s7] = __hip_atomic_load(ex + pidx[s7], __ATOMIC_RELAXED,
                                    __HIP_MEMORY_SCOPE_AGENT);
      #pragma unroll
      for (int s7 = 0; s7 < 7; ++s7)
        if ((need & (1u << s7)) && (unsigned)(v[s7] >> 32) == (unsigned)NT) {
          hv[s7] = __uint_as_float((unsigned)v[s7]);
          need &= ~(1u << s7);
        }
    }
    #pragma unroll
    for (int s7 = 0; s7 < 7; ++s7) {
      int ps = (s7 < p) ? s7 : s7 + 1;     // p==0 -> ps = s7+1
      sum += hv[s7] * W_out[ps * 32 + jj];
    }
    #pragma unroll
    for (int m = 16; m >= 1; m >>= 1) sum += __shfl_xor(sum, m, 64);
    if (jj == 0) out[g * 8 + bl] = sum + b_out[0];
  }
}

extern "C" void kernel_launch(void* const* d_in, const int* in_sizes, int n_in,
                              void* d_out, int out_size, void* d_ws, size_t ws_size,
                              hipStream_t stream) {
  (void)in_sizes; (void)n_in; (void)out_size; (void)ws_size;
  const float* xd    = (const float*)d_in[0];
  const float* w     = (const float*)d_in[1];
  const float* W_ih  = (const float*)d_in[2];
  const float* b_ih  = (const float*)d_in[3];
  const float* W_hh  = (const float*)d_in[4];
  const float* b_hh  = (const float*)d_in[5];
  const float* W_out = (const float*)d_in[6];
  const float* b_out = (const float*)d_in[7];
  // ws: 2*16384 uint64 = 256 KB tagged-h exchange. No memset needed: the
  // 0xAA poison tag (0xAAAAAAAA) can never equal a valid step tag (<=2048).
  uint64_t* ex = (uint64_t*)d_ws;
  lstm_persist<<<dim3(64), dim3(256), 0, stream>>>(
      xd, w, W_ih, b_ih, W_hh, b_hh, W_out, b_out, (float*)d_out, ex);
}